// Round 3
// baseline (192.675 us; speedup 1.0000x reference)
//
#include <hip/hip_runtime.h>

// Depthwise 7x7 'same' conv, fp32. B=16, C=256, H=W=64.
// No LDS. One wave per (b,c) plane (4096 waves = 4 waves/SIMD exactly).
// Each lane owns an 8-wide x 8-high output tile (64 acc VGPRs),
// output-stationary, streaming 14 input rows directly from global.
// tx = lane&7 (8 col-tiles x 8 = 64 wide), sy = lane>>3 (8 row-strips x 8 = 64 high).
// Weights wave-uniform -> scalar regs. __launch_bounds__(256,4) -> VGPR<=128.

__global__ __launch_bounds__(256, 4)
void dwconv7x7_regs8x8(const float* __restrict__ x,
                       const float* __restrict__ weight,
                       const float* __restrict__ bias,
                       float* __restrict__ out) {
    const int tid  = threadIdx.x;
    const int lane = tid & 63;
    const int wid  = tid >> 6;
    const int plane = blockIdx.x * 4 + wid;  // 0..4095 = b*256 + c
    const int c = __builtin_amdgcn_readfirstlane(plane & 255);

    // ---- per-channel weights + bias (wave-uniform -> SALU/scalar) ----
    const float* wp = weight + c * 49;
    float wk[49];
#pragma unroll
    for (int k = 0; k < 49; ++k) wk[k] = wp[k];
    const float bv = bias[c];

    const int tx = lane & 7;          // 8 tiles across width
    const int sy = lane >> 3;         // 8 strips down height
    const int wb = tx * 8;            // output col base
    const int hb = sy * 8;            // output row base

    const float* xp = x + (size_t)plane * 4096;

    float acc[8][8];
#pragma unroll
    for (int i = 0; i < 8; ++i)
#pragma unroll
        for (int j = 0; j < 8; ++j) acc[i][j] = 0.f;

    const int offm = (tx > 0) ? (wb - 4) : wb;   // clamped aligned left read
    const int offp = (tx < 7) ? (wb + 8) : wb;   // clamped aligned right read

    // Stream input rows hb-3 .. hb+10.
#pragma unroll
    for (int j = 0; j < 14; ++j) {
        const int r  = hb - 3 + j;
        const int rc = min(max(r, 0), 63);
        const float* rowp = xp + rc * 64;
        const bool mrow = (r >= 0) && (r < 64);
        const bool mm = mrow && (tx > 0);
        const bool mp = mrow && (tx < 7);

        float4 qm = *reinterpret_cast<const float4*>(rowp + offm);
        float4 q0 = *reinterpret_cast<const float4*>(rowp + wb);
        float4 q1 = *reinterpret_cast<const float4*>(rowp + wb + 4);
        float4 qp = *reinterpret_cast<const float4*>(rowp + offp);

        float f[16];
        f[0]  = mm   ? qm.x : 0.f;
        f[1]  = mm   ? qm.y : 0.f;
        f[2]  = mm   ? qm.z : 0.f;
        f[3]  = mm   ? qm.w : 0.f;
        f[4]  = mrow ? q0.x : 0.f;
        f[5]  = mrow ? q0.y : 0.f;
        f[6]  = mrow ? q0.z : 0.f;
        f[7]  = mrow ? q0.w : 0.f;
        f[8]  = mrow ? q1.x : 0.f;
        f[9]  = mrow ? q1.y : 0.f;
        f[10] = mrow ? q1.z : 0.f;
        f[11] = mrow ? q1.w : 0.f;
        f[12] = mp   ? qp.x : 0.f;
        f[13] = mp   ? qp.y : 0.f;
        f[14] = mp   ? qp.z : 0.f;
        f[15] = mp   ? qp.w : 0.f;

        // f covers input cols wb-4 .. wb+11; needed: wb-3 .. wb+10.
        // output col wb+jj, tap kc -> input col wb+jj-3+kc = f[1+jj+kc]
#pragma unroll
        for (int oi = 0; oi < 8; ++oi) {
            const int kr = j - oi;
            if (kr >= 0 && kr < 7) {
#pragma unroll
                for (int jj = 0; jj < 8; ++jj) {
#pragma unroll
                    for (int kc = 0; kc < 7; ++kc) {
                        acc[oi][jj] += f[1 + jj + kc] * wk[kr * 7 + kc];
                    }
                }
            }
        }
    }

    // ---- write 8 rows x 2 float4 each, plus bias ----
    float* op = out + (size_t)plane * 4096 + (size_t)hb * 64 + wb;
#pragma unroll
    for (int oi = 0; oi < 8; ++oi) {
        float4 v0, v1;
        v0.x = acc[oi][0] + bv;
        v0.y = acc[oi][1] + bv;
        v0.z = acc[oi][2] + bv;
        v0.w = acc[oi][3] + bv;
        v1.x = acc[oi][4] + bv;
        v1.y = acc[oi][5] + bv;
        v1.z = acc[oi][6] + bv;
        v1.w = acc[oi][7] + bv;
        *reinterpret_cast<float4*>(op + oi * 64)     = v0;
        *reinterpret_cast<float4*>(op + oi * 64 + 4) = v1;
    }
}

extern "C" void kernel_launch(void* const* d_in, const int* in_sizes, int n_in,
                              void* d_out, int out_size, void* d_ws, size_t ws_size,
                              hipStream_t stream) {
    const float* x      = (const float*)d_in[0];
    const float* weight = (const float*)d_in[1];
    const float* bias   = (const float*)d_in[2];
    float* out          = (float*)d_out;
    (void)in_sizes; (void)n_in; (void)out_size; (void)d_ws; (void)ws_size;

    // 4096 waves = 1024 blocks x 256 threads (4 waves/block, 1 wave per plane)
    dim3 grid(1024);
    dim3 block(256);
    dwconv7x7_regs8x8<<<grid, block, 0, stream>>>(x, weight, bias, out);
}

// Round 4
// 40.645 us; speedup vs baseline: 4.7405x; 4.7405x over previous
//
#include <hip/hip_runtime.h>

// Depthwise 7x7 'same' conv, fp32. B=16, C=256, H=W=64.
// One block (128 threads) per (b,c) plane. Whole plane staged in a
// zero-padded LDS tile so the hot loop has ZERO boundary selects.
//
// LDS layout: tile[row][80], row = input_row + 3 (rows 0..69).
//   Input col c lives at LDS col c + 4 + 4*p(row), p(row) = (row>>2)&1.
//   The per-4-row 4-float shift makes wave64 ds_read_b128 hit all 32
//   banks (without it, lane quads cover only 16 banks -> 2x DS time;
//   this was R0's 1.07e7-cycle bank-conflict bill).
// Per thread: 8-wide x 4-high output tile = 32 accumulators (64-acc
// spilled in R3; 32 is known-safe). 10 rows x 4 ds_read_b128 each.
#define LDSW 80
#define LDSH 70

__global__ void dwconv7x7_lds(const float* __restrict__ x,
                              const float* __restrict__ weight,
                              const float* __restrict__ bias,
                              float* __restrict__ out) {
    __shared__ float tile[LDSH * LDSW];

    const int tid   = threadIdx.x;     // 0..127
    const int plane = blockIdx.x;      // b*256 + c
    const int c     = plane & 255;     // uniform -> SGPR

    // ---- zero the whole tile (1400 float4) ----
    const float4 z4 = make_float4(0.f, 0.f, 0.f, 0.f);
#pragma unroll
    for (int k = 0; k < 11; ++k) {
        int q = tid + k * 128;
        if (q < (LDSH * LDSW) / 4)
            *reinterpret_cast<float4*>(&tile[q * 4]) = z4;
    }

    // ---- per-channel weights + bias (block-uniform -> scalar loads) ----
    const float* wp = weight + c * 49;
    float wk[49];
#pragma unroll
    for (int k = 0; k < 49; ++k) wk[k] = wp[k];
    const float bv = bias[c];

    __syncthreads();

    // ---- stage plane into LDS (coalesced float4, swizzled dst) ----
    const float* xp = x + (size_t)plane * 4096;
#pragma unroll
    for (int k = 0; k < 8; ++k) {
        int g   = tid + k * 128;       // float4 index in plane, 1024 total
        int h   = g >> 4;              // input row
        int w4  = g & 15;              // float4 col index
        int row = h + 3;
        int p   = (row >> 2) & 1;
        float4 v = *reinterpret_cast<const float4*>(&xp[g * 4]);
        *reinterpret_cast<float4*>(&tile[row * LDSW + 4 + w4 * 4 + p * 4]) = v;
    }
    __syncthreads();

    // ---- compute: 8 wide x 4 high per thread ----
    const int tx = tid & 7;            // 8 col tiles
    const int sy = tid >> 3;           // 16 row strips
    const int wb = tx * 8;             // output col base
    const int hb = sy * 4;             // output row base

    float acc[4][8];
#pragma unroll
    for (int i = 0; i < 4; ++i)
#pragma unroll
        for (int j = 0; j < 8; ++j) acc[i][j] = 0.f;

    // f[m] = x[input_row][wb-4+m], m=0..15 (zeros materialized by padding)
#pragma unroll
    for (int j = 0; j < 10; ++j) {
        const int row = hb + j;                 // LDS row (input row hb-3+j)
        const int p   = (row >> 2) & 1;
        const float* rp = &tile[row * LDSW + wb + 4 * p];
        float4 q0 = *reinterpret_cast<const float4*>(rp);
        float4 q1 = *reinterpret_cast<const float4*>(rp + 4);
        float4 q2 = *reinterpret_cast<const float4*>(rp + 8);
        float4 q3 = *reinterpret_cast<const float4*>(rp + 12);
        float f[16] = {q0.x, q0.y, q0.z, q0.w,
                       q1.x, q1.y, q1.z, q1.w,
                       q2.x, q2.y, q2.z, q2.w,
                       q3.x, q3.y, q3.z, q3.w};
        // input col wb+jj+kc-3 = f[jj+kc+1]
#pragma unroll
        for (int oi = 0; oi < 4; ++oi) {
            const int kr = j - oi;
            if (kr >= 0 && kr < 7) {
#pragma unroll
                for (int jj = 0; jj < 8; ++jj) {
#pragma unroll
                    for (int kc = 0; kc < 7; ++kc) {
                        acc[oi][jj] += f[jj + kc + 1] * wk[kr * 7 + kc];
                    }
                }
            }
        }
    }

    // ---- write 4 rows x 2 float4, plus bias (coalesced) ----
    float* op = out + (size_t)plane * 4096 + (size_t)hb * 64 + wb;
#pragma unroll
    for (int oi = 0; oi < 4; ++oi) {
        float4 v0, v1;
        v0.x = acc[oi][0] + bv;
        v0.y = acc[oi][1] + bv;
        v0.z = acc[oi][2] + bv;
        v0.w = acc[oi][3] + bv;
        v1.x = acc[oi][4] + bv;
        v1.y = acc[oi][5] + bv;
        v1.z = acc[oi][6] + bv;
        v1.w = acc[oi][7] + bv;
        *reinterpret_cast<float4*>(op + oi * 64)     = v0;
        *reinterpret_cast<float4*>(op + oi * 64 + 4) = v1;
    }
}

extern "C" void kernel_launch(void* const* d_in, const int* in_sizes, int n_in,
                              void* d_out, int out_size, void* d_ws, size_t ws_size,
                              hipStream_t stream) {
    const float* x      = (const float*)d_in[0];
    const float* weight = (const float*)d_in[1];
    const float* bias   = (const float*)d_in[2];
    float* out          = (float*)d_out;
    (void)in_sizes; (void)n_in; (void)out_size; (void)d_ws; (void)ws_size;

    dim3 grid(4096);    // one block per (b, c) plane
    dim3 block(128);
    dwconv7x7_lds<<<grid, block, 0, stream>>>(x, weight, bias, out);
}

// Round 5
// 34.809 us; speedup vs baseline: 5.5352x; 1.1677x over previous
//
#include <hip/hip_runtime.h>

// Depthwise 7x7 'same' conv, fp32. B=16, C=256, H=W=64.
// R1 structure (global loads, no LDS, wave = half-plane, lane = 4w x 8h
// output tile, 32 acc) + 3-deep software-prefetch ring so VMEM latency
// hides under FMAs. __launch_bounds__(256,2) lifts the VGPR cap so the
// ring (~9 dwordx4 in flight) stays in registers (R1's VGPR=64 left no
// headroom -> loads issued at use -> 60% VALU idle).

__global__ __launch_bounds__(256, 2)
void dwconv7x7_pipe(const float* __restrict__ x,
                    const float* __restrict__ weight,
                    const float* __restrict__ bias,
                    float* __restrict__ out) {
    const int tid  = threadIdx.x;
    const int lane = tid & 63;
    const int wid  = tid >> 6;
    const int gw   = blockIdx.x * 4 + wid;   // 0..8191
    const int plane = gw >> 1;               // b*256 + c
    const int half  = gw & 1;
    const int c = __builtin_amdgcn_readfirstlane(plane & 255);

    // per-channel weights + bias (wave-uniform -> SGPR file)
    const float* wp = weight + c * 49;
    float wk[49];
#pragma unroll
    for (int k = 0; k < 49; ++k) wk[k] = wp[k];
    const float bv = bias[c];

    const int tx = lane & 15;        // 16 tiles across width
    const int sy = lane >> 4;        // 4 strips per half-plane
    const int wb = tx * 4;           // output col base
    const int hb = half * 32 + sy * 8;

    const float* xp = x + (size_t)plane * 4096;
    const int offm = (tx > 0)  ? (wb - 4) : wb;   // clamped aligned left
    const int offp = (tx < 15) ? (wb + 4) : wb;   // clamped aligned right

    // ---- 3-deep prefetch ring: rows j, j+1, j+2 in flight ----
    float4 rm[3], r0[3], rp[3];
#pragma unroll
    for (int j = 0; j < 3; ++j) {
        const int r  = hb - 3 + j;
        const int rc = min(max(r, 0), 63);
        const float* rowp = xp + rc * 64;
        rm[j] = *reinterpret_cast<const float4*>(rowp + offm);
        r0[j] = *reinterpret_cast<const float4*>(rowp + wb);
        rp[j] = *reinterpret_cast<const float4*>(rowp + offp);
    }

    float acc[8][4];
#pragma unroll
    for (int i = 0; i < 8; ++i)
#pragma unroll
        for (int j = 0; j < 4; ++j) acc[i][j] = 0.f;

#pragma unroll
    for (int j = 0; j < 14; ++j) {
        const int s = j % 3;                 // constant after unroll
        const int r = hb - 3 + j;
        const bool mrow = (r >= 0) && (r < 64);
        const bool mm = mrow && (tx > 0);
        const bool mp = mrow && (tx < 15);

        // f[i] = x[r][wb-3+i], i = 0..9 (masked to zero outside)
        float f[10];
        f[0] = mm   ? rm[s].y : 0.f;
        f[1] = mm   ? rm[s].z : 0.f;
        f[2] = mm   ? rm[s].w : 0.f;
        f[3] = mrow ? r0[s].x : 0.f;
        f[4] = mrow ? r0[s].y : 0.f;
        f[5] = mrow ? r0[s].z : 0.f;
        f[6] = mrow ? r0[s].w : 0.f;
        f[7] = mp   ? rp[s].x : 0.f;
        f[8] = mp   ? rp[s].y : 0.f;
        f[9] = mp   ? rp[s].z : 0.f;

        // ring slot s is free now -> issue row j+3 into it
        if (j + 3 < 14) {
            const int rn  = hb - 3 + (j + 3);
            const int rnc = min(max(rn, 0), 63);
            const float* rowp = xp + rnc * 64;
            rm[s] = *reinterpret_cast<const float4*>(rowp + offm);
            r0[s] = *reinterpret_cast<const float4*>(rowp + wb);
            rp[s] = *reinterpret_cast<const float4*>(rowp + offp);
        }
        // pin the issued loads above the FMA block (registers unaffected)
        asm volatile("" ::: "memory");

        // input col wb+jj-3+kc = f[jj+kc]
#pragma unroll
        for (int oi = 0; oi < 8; ++oi) {
            const int kr = j - oi;
            if (kr >= 0 && kr < 7) {
#pragma unroll
                for (int jj = 0; jj < 4; ++jj) {
#pragma unroll
                    for (int kc = 0; kc < 7; ++kc) {
                        acc[oi][jj] += f[jj + kc] * wk[kr * 7 + kc];
                    }
                }
            }
        }
    }

    // ---- write 8 rows x float4, plus bias ----
    float* op = out + (size_t)plane * 4096 + (size_t)hb * 64 + wb;
#pragma unroll
    for (int oi = 0; oi < 8; ++oi) {
        float4 v;
        v.x = acc[oi][0] + bv;
        v.y = acc[oi][1] + bv;
        v.z = acc[oi][2] + bv;
        v.w = acc[oi][3] + bv;
        *reinterpret_cast<float4*>(op + oi * 64) = v;
    }
}

extern "C" void kernel_launch(void* const* d_in, const int* in_sizes, int n_in,
                              void* d_out, int out_size, void* d_ws, size_t ws_size,
                              hipStream_t stream) {
    const float* x      = (const float*)d_in[0];
    const float* weight = (const float*)d_in[1];
    const float* bias   = (const float*)d_in[2];
    float* out          = (float*)d_out;
    (void)in_sizes; (void)n_in; (void)out_size; (void)d_ws; (void)ws_size;

    // 8192 waves = 2048 blocks x 256 threads (4 waves/block)
    dim3 grid(2048);
    dim3 block(256);
    dwconv7x7_pipe<<<grid, block, 0, stream>>>(x, weight, bias, out);
}